// Round 5
// baseline (449.641 us; speedup 1.0000x reference)
//
#include <hip/hip_runtime.h>

#define N 8192
#define F 128
#define NEWF 64
#define ALPHA 0.2f
#define JSPLIT 8
#define JW (N / JSPLIT)     // 1024 j per block
#define NCH (JW / 32)       // 32 chunks of K=32
#define RB 64               // rows per block (4 waves x 16)

typedef float f32x4 __attribute__((ext_vector_type(4)));
typedef short short8 __attribute__((ext_vector_type(8)));

// ---------------------------------------------------------------------------
// Kernel 0: bit-pack A into the lane-contiguous mask layout k_main consumes.
//   mask byte at ((row*JSPLIT+js)*4+lg)*32 + c  holds bits for
//   j = js*JW + c*32 + lg*8 + b  (b = bit index 0..7).
//   Pure streaming: 256 MB read / 8 MB write, no barriers, deep MLP.
// ---------------------------------------------------------------------------
__global__ void __launch_bounds__(256) k_pack(const int* __restrict__ A,
                                              unsigned* __restrict__ mask) {
    const int t = threadIdx.x;
    const int row = blockIdx.x * 8 + (t >> 5);
    const int u = t & 31;
    const int js = u >> 2, lg = u & 3;
    const int4* src = (const int4*)(A + (size_t)row * N + js * JW + lg * 8);
    unsigned* dst = mask + (((size_t)row * JSPLIT + js) * 4 + lg) * 8;
#pragma unroll 4
    for (int c4 = 0; c4 < 8; ++c4) {
        unsigned word = 0;
#pragma unroll
        for (int k = 0; k < 4; ++k) {
            const int4* p = src + (size_t)(c4 * 4 + k) * 8;   // += c*32 ints
            int4 a0 = p[0], a1 = p[1];
            unsigned b = 0;
            b |= (a0.x != 0) ? 1u   : 0u;
            b |= (a0.y != 0) ? 2u   : 0u;
            b |= (a0.z != 0) ? 4u   : 0u;
            b |= (a0.w != 0) ? 8u   : 0u;
            b |= (a1.x != 0) ? 16u  : 0u;
            b |= (a1.y != 0) ? 32u  : 0u;
            b |= (a1.z != 0) ? 64u  : 0u;
            b |= (a1.w != 0) ? 128u : 0u;
            word |= b << (8 * k);
        }
        dst[c4] = word;
    }
}

// ---------------------------------------------------------------------------
// Kernel 1: h = X @ W (f32), s = h @ a_self, n = h @ a_neigh
// ---------------------------------------------------------------------------
__global__ void k_hsn(const float* __restrict__ X, const float* __restrict__ W,
                      const float* __restrict__ a_self, const float* __restrict__ a_neigh,
                      float* __restrict__ h, float* __restrict__ s, float* __restrict__ n) {
    int row = blockIdx.x * 4 + (threadIdx.x >> 6);
    int l = threadIdx.x & 63;
    const float* xr = X + (size_t)row * F;
    float acc = 0.0f;
#pragma unroll 8
    for (int f = 0; f < F; ++f) acc += xr[f] * W[f * NEWF + l];
    h[(size_t)row * NEWF + l] = acc;
    float ts = acc * a_self[l];
    float tn = acc * a_neigh[l];
#pragma unroll
    for (int off = 32; off; off >>= 1) {
        ts += __shfl_xor(ts, off);
        tn += __shfl_xor(tn, off);
    }
    if (l == 0) { s[row] = ts; n[row] = tn; }
}

// ---------------------------------------------------------------------------
// Kernel 2: transpose h, split into bf16 hi/lo planes hT[c][j]
// ---------------------------------------------------------------------------
__global__ void k_tr(const float* __restrict__ h, unsigned short* __restrict__ hThi,
                     unsigned short* __restrict__ hTlo) {
    __shared__ float tile[64][65];
    const int t = threadIdx.x;
    const int j0 = blockIdx.x * 64;
    {
        const int jr = t >> 2, cs = (t & 3) * 16;
        const float4* src = (const float4*)(h + (size_t)(j0 + jr) * NEWF + cs);
#pragma unroll
        for (int q = 0; q < 4; ++q) {
            float4 v = src[q];
            tile[jr][cs + q * 4 + 0] = v.x; tile[jr][cs + q * 4 + 1] = v.y;
            tile[jr][cs + q * 4 + 2] = v.z; tile[jr][cs + q * 4 + 3] = v.w;
        }
    }
    __syncthreads();
    {
        const int c = t >> 2, js = (t & 3) * 16;
        short8 hi0 = {}, hi1 = {}, lo0 = {}, lo1 = {};
#pragma unroll
        for (int k = 0; k < 16; ++k) {
            float v = tile[js + k][c];
            unsigned xb = __float_as_uint(v);
            short hb = (short)(xb >> 16);
            float lof = v - __uint_as_float(xb & 0xffff0000u);
            short lb = (short)(__float_as_uint(lof) >> 16);
            if (k < 8) { hi0[k] = hb; lo0[k] = lb; }
            else       { hi1[k - 8] = hb; lo1[k - 8] = lb; }
        }
        size_t off = (size_t)c * N + j0 + js;
        *(short8*)(hThi + off)     = hi0;
        *(short8*)(hThi + off + 8) = hi1;
        *(short8*)(hTlo + off)     = lo0;
        *(short8*)(hTlo + off + 8) = lo1;
    }
}

// ---------------------------------------------------------------------------
// Kernel 3: nmax = max_j n[j]
// ---------------------------------------------------------------------------
__global__ void k_nmax(const float* __restrict__ n, float* __restrict__ nmax) {
    __shared__ float red[1024];
    int t = threadIdx.x;
    float4 v0 = ((const float4*)n)[t];
    float4 v1 = ((const float4*)n)[t + 1024];
    float m = fmaxf(fmaxf(fmaxf(v0.x, v0.y), fmaxf(v0.z, v0.w)),
                    fmaxf(fmaxf(v1.x, v1.y), fmaxf(v1.z, v1.w)));
    red[t] = m;
    __syncthreads();
    for (int off = 512; off; off >>= 1) {
        if (t < off) red[t] = fmaxf(red[t], red[t + off]);
        __syncthreads();
    }
    if (t == 0) nmax[0] = red[0];
}

// ---------------------------------------------------------------------------
// Kernel 4: fused attention, split-bf16 MFMA, B via double-buffered LDS.
//   A arrives as an 8 MB bitmask; each lane's whole j-slice dependency is
//   8 uints (32 B), streamed 1 word (4 chunks) ahead in a single register.
//   Main loop has NO HBM-latency dependence (n, hT are L2-resident).
// ---------------------------------------------------------------------------
__global__ void __launch_bounds__(256, 4) k_main(
        const unsigned* __restrict__ mask, const float* __restrict__ s,
        const float* __restrict__ n, const float* __restrict__ nmaxp,
        const unsigned short* __restrict__ hThi, const unsigned short* __restrict__ hTlo,
        float* __restrict__ pacc, float* __restrict__ pz) {
    __shared__ __align__(16) unsigned short bt[2][2][64][32];   // 16 KB dbuf B tiles

    const int tid = threadIdx.x;
    const int w = tid >> 6, l = tid & 63;
    const int lr = l & 15, lg = l >> 4;

    const int rb = blockIdx.x / JSPLIT;
    const int js = blockIdx.x % JSPLIT;
    const int r0 = rb * RB + w * 16;
    const int jb = js * JW;

    const float sval = s[r0 + lr];
    const float tM = sval + nmaxp[0];
    const float Mv = fmaxf(tM, ALPHA * tM);
    float zacc = 0.0f;

    f32x4 acc0 = {0.f,0.f,0.f,0.f}, acc1 = {0.f,0.f,0.f,0.f};
    f32x4 acc2 = {0.f,0.f,0.f,0.f}, acc3 = {0.f,0.f,0.f,0.f};

    // staging mapping: thread t stages row t>>2, j-sub (t&3)*8 (16B each plane)
    const int srow = tid >> 2, sj = (tid & 3) * 8;
    const short8* ghi = (const short8*)(hThi + (size_t)srow * N + jb + sj);
    const short8* glo = (const short8*)(hTlo + (size_t)srow * N + jb + sj);

    // per-lane mask word stream: 8 uints cover the whole 1024-j slice
    const unsigned* mp = mask + (((size_t)(r0 + lr) * JSPLIT + js) * 4 + lg) * 8;
    unsigned mpref = mp[0];

    // ---- prologue: stage chunk 0 ----
    {
        short8 vhi = ghi[0];
        short8 vlo = glo[0];
        *(short8*)&bt[0][0][srow][sj] = vhi;
        *(short8*)&bt[0][1][srow][sj] = vlo;
    }
    asm volatile("s_waitcnt lgkmcnt(0)" ::: "memory");
    __builtin_amdgcn_s_barrier();

    const float4* npv = (const float4*)(n + jb + lg * 8);
    float4 nv0 = npv[0], nv1 = npv[1];
    unsigned mword = 0;

    for (int c = 0; c < NCH; ++c) {
        const int p = c & 1;
        const int cn = (c + 1 < NCH) ? c + 1 : 0;   // wrap: dummy on last iter

        // ---- rotate mask word every 4 chunks; prefetch the next one ----
        if ((c & 3) == 0) {
            mword = mpref;
            mpref = mp[((c >> 2) + 1) & 7];          // wrap: dummy reload
        }
        const unsigned mbyte = (mword >> ((c & 3) * 8)) & 0xffu;

        // ---- issue next-chunk loads FIRST, pin them with sched_barrier ----
        short8 nhi = ghi[cn * 4];
        short8 nlo = glo[cn * 4];
        float4 nn0 = npv[cn * 8], nn1 = npv[cn * 8 + 1];
        __builtin_amdgcn_sched_barrier(0);

        // ---- e-phase: 8 e's per lane straight into A-fragments ----
        float nf[8] = {nv0.x, nv0.y, nv0.z, nv0.w, nv1.x, nv1.y, nv1.z, nv1.w};
        short8 ahi, alo;
#pragma unroll
        for (int j = 0; j < 8; ++j) {
            float t  = sval + nf[j];
            float lv = fmaxf(t, ALPHA * t);
            float ex = __expf(lv - Mv);
            ex = (mbyte & (1u << j)) ? ex : 0.0f;
            zacc += ex;
            unsigned xb = __float_as_uint(ex);
            ahi[j] = (short)(xb >> 16);
            float lof = ex - __uint_as_float(xb & 0xffff0000u);
            alo[j] = (short)(__float_as_uint(lof) >> 16);
        }

        // ---- B fragments from LDS ----
        short8 B0h = *(const short8*)&bt[p][0][lr +  0][lg * 8];
        short8 B1h = *(const short8*)&bt[p][0][lr + 16][lg * 8];
        short8 B2h = *(const short8*)&bt[p][0][lr + 32][lg * 8];
        short8 B3h = *(const short8*)&bt[p][0][lr + 48][lg * 8];
        short8 B0l = *(const short8*)&bt[p][1][lr +  0][lg * 8];
        short8 B1l = *(const short8*)&bt[p][1][lr + 16][lg * 8];
        short8 B2l = *(const short8*)&bt[p][1][lr + 32][lg * 8];
        short8 B3l = *(const short8*)&bt[p][1][lr + 48][lg * 8];

        // ---- 12 MFMAs: hi*hi + hi*lo + lo*hi ----
        acc0 = __builtin_amdgcn_mfma_f32_16x16x32_bf16(ahi, B0h, acc0, 0, 0, 0);
        acc1 = __builtin_amdgcn_mfma_f32_16x16x32_bf16(ahi, B1h, acc1, 0, 0, 0);
        acc2 = __builtin_amdgcn_mfma_f32_16x16x32_bf16(ahi, B2h, acc2, 0, 0, 0);
        acc3 = __builtin_amdgcn_mfma_f32_16x16x32_bf16(ahi, B3h, acc3, 0, 0, 0);
        acc0 = __builtin_amdgcn_mfma_f32_16x16x32_bf16(ahi, B0l, acc0, 0, 0, 0);
        acc1 = __builtin_amdgcn_mfma_f32_16x16x32_bf16(ahi, B1l, acc1, 0, 0, 0);
        acc2 = __builtin_amdgcn_mfma_f32_16x16x32_bf16(ahi, B2l, acc2, 0, 0, 0);
        acc3 = __builtin_amdgcn_mfma_f32_16x16x32_bf16(ahi, B3l, acc3, 0, 0, 0);
        acc0 = __builtin_amdgcn_mfma_f32_16x16x32_bf16(alo, B0h, acc0, 0, 0, 0);
        acc1 = __builtin_amdgcn_mfma_f32_16x16x32_bf16(alo, B1h, acc1, 0, 0, 0);
        acc2 = __builtin_amdgcn_mfma_f32_16x16x32_bf16(alo, B2h, acc2, 0, 0, 0);
        acc3 = __builtin_amdgcn_mfma_f32_16x16x32_bf16(alo, B3h, acc3, 0, 0, 0);

        // ---- write next B tile, manual barrier ----
        *(short8*)&bt[p ^ 1][0][srow][sj] = nhi;
        *(short8*)&bt[p ^ 1][1][srow][sj] = nlo;
        asm volatile("s_waitcnt lgkmcnt(0)" ::: "memory");
        __builtin_amdgcn_s_barrier();
        __builtin_amdgcn_sched_barrier(0);

        nv0 = nn0; nv1 = nn1;
    }

    // ---- z reduce over the 4 k-groups of each row ----
    zacc += __shfl_xor(zacc, 16);
    zacc += __shfl_xor(zacc, 32);

    // ---- write partials ----
    float* pa = pacc + ((size_t)js * N + r0) * NEWF;
#pragma unroll
    for (int r = 0; r < 4; ++r) {
        int row = lg * 4 + r;
        pa[(size_t)row * NEWF +  0 + lr] = acc0[r];
        pa[(size_t)row * NEWF + 16 + lr] = acc1[r];
        pa[(size_t)row * NEWF + 32 + lr] = acc2[r];
        pa[(size_t)row * NEWF + 48 + lr] = acc3[r];
    }
    if (l < 16) pz[(size_t)js * N + r0 + lr] = zacc;
}

// ---------------------------------------------------------------------------
// Kernel 5: finalize — sum partials, divide, relu
// ---------------------------------------------------------------------------
__global__ void k_fin(const float* __restrict__ pacc, const float* __restrict__ pz,
                      float* __restrict__ out) {
    int t = blockIdx.x * 256 + threadIdx.x;     // 0 .. N*NEWF-1
    int i = t >> 6, k = t & 63;
    float v = 0.0f, z = 0.0f;
#pragma unroll
    for (int psl = 0; psl < JSPLIT; ++psl) {
        v += pacc[((size_t)psl * N + i) * NEWF + k];
        z += pz[(size_t)psl * N + i];
    }
    out[t] = fmaxf(v / z, 0.0f);
}

// ---------------------------------------------------------------------------
extern "C" void kernel_launch(void* const* d_in, const int* in_sizes, int n_in,
                              void* d_out, int out_size, void* d_ws, size_t ws_size,
                              hipStream_t stream) {
    const float* X       = (const float*)d_in[0];
    const int*   A       = (const int*)d_in[1];
    const float* W       = (const float*)d_in[2];
    const float* a_self  = (const float*)d_in[3];
    const float* a_neigh = (const float*)d_in[4];
    float* out = (float*)d_out;

    float* wsf = (float*)d_ws;
    float* h    = wsf;                        // N*NEWF f32 (2MB)
    float* s    = h + (size_t)N * NEWF;       // N
    float* nv   = s + N;                      // N
    float* nmax = nv + N;                     // 4
    unsigned short* hThi = (unsigned short*)(nmax + 4);   // N*NEWF ushort (1MB)
    unsigned short* hTlo = hThi + (size_t)N * NEWF;       // N*NEWF ushort (1MB)
    float* pacc = (float*)(hTlo + (size_t)N * NEWF);      // JSPLIT*N*NEWF f32 (16MB)
    float* pz   = pacc + (size_t)JSPLIT * N * NEWF;       // JSPLIT*N f32 (256KB)
    unsigned* mask = (unsigned*)(pz + (size_t)JSPLIT * N); // N*N/32 uints (8MB)

    k_pack<<<N / 8,        256, 0, stream>>>(A, mask);
    k_hsn <<<N / 4,        256, 0, stream>>>(X, W, a_self, a_neigh, h, s, nv);
    k_tr  <<<N / 64,       256, 0, stream>>>(h, hThi, hTlo);
    k_nmax<<<1,           1024, 0, stream>>>(nv, nmax);
    k_main<<<(N / RB) * JSPLIT, 256, 0, stream>>>(mask, s, nv, nmax, hThi, hTlo, pacc, pz);
    k_fin <<<(N * NEWF) / 256, 256, 0, stream>>>(pacc, pz, out);
}